// Round 10
// baseline (153.733 us; speedup 1.0000x reference)
//
#include <hip/hip_runtime.h>
#include <stdint.h>

#define D_MODEL 1024
#define T_LEN   4096
#define B_SZ    4
#define NROWS   (B_SZ * T_LEN)   // 16384
#define NPROJ   (2 * D_MODEL)    // 2048
#define CHUNK   32               // rows of T per k_post block

#define BM 256
#define BN 256
#define BK 64
#define NT (D_MODEL / BK)        // 16 K-steps

typedef __attribute__((ext_vector_type(8))) __bf16 bf16x8;
typedef __attribute__((ext_vector_type(4))) float  f32x4;

using as1_void = __attribute__((address_space(1))) void;
using as3_void = __attribute__((address_space(3))) void;

__device__ inline float bf2f(unsigned short u) {
    union { unsigned int i; float f; } v; v.i = ((unsigned int)u) << 16; return v.f;
}
__device__ inline unsigned short f2bf(float f) {
    union { float f; unsigned int i; } v; v.f = f;
    return (unsigned short)((v.i + 0x7fffu + ((v.i >> 16) & 1u)) >> 16);
}
__device__ inline float sigmoidf(float x) { return 1.0f / (1.0f + __expf(-x)); }

// ---------------- K0: fused converts (x fp32->bf16, W fp32->bf16 transposed) ----------------
__global__ __launch_bounds__(256) void k_cvt(const float* __restrict__ x,
                                             unsigned short* __restrict__ xb,
                                             const float* __restrict__ W,
                                             unsigned short* __restrict__ wt) {
    __shared__ unsigned short tile[32][33];
    int bid = blockIdx.x;
    if (bid < (NROWS * D_MODEL) / (256 * 4)) {
        int i = (bid * 256 + threadIdx.x) * 4;
        float4 v = *reinterpret_cast<const float4*>(x + i);
        ushort4 o;
        o.x = f2bf(v.x); o.y = f2bf(v.y); o.z = f2bf(v.z); o.w = f2bf(v.w);
        *reinterpret_cast<ushort4*>(xb + i) = o;
    } else {
        bid -= (NROWS * D_MODEL) / (256 * 4);
        int n0 = (bid & 63) * 32, k0 = (bid >> 6) * 32;
        int c = threadIdx.x & 31, r = threadIdx.x >> 5;  // r in 0..7
        #pragma unroll
        for (int i = 0; i < 4; i++) {
            int kk = r + i * 8;
            tile[kk][c] = f2bf(W[(uint64_t)(k0 + kk) * NPROJ + n0 + c]);
        }
        __syncthreads();
        #pragma unroll
        for (int i = 0; i < 4; i++) {
            int nn = r + i * 8;
            wt[(uint64_t)(n0 + nn) * D_MODEL + k0 + c] = tile[c][nn];
        }
    }
}

// ---------------- K1: GEMM proj = xb @ wt^T + bias, store bf16 ----------------
// EXACT R3 kernel (verified 85.5us x5 runs, 0 bank conflicts). DO NOT touch
// the epilogue: any branch/extra math there perturbs the K-loop schedule
// (R5: +31us, R6: +14us).
__global__ __launch_bounds__(512, 2) void k_gemm(const unsigned short* __restrict__ xb,
                                                 const unsigned short* __restrict__ wt,
                                                 const float* __restrict__ bias,
                                                 unsigned short* __restrict__ projb) {
    __shared__ __align__(16) unsigned short As[2 * BM * BK];  // 64 KB
    __shared__ __align__(16) unsigned short Bs[2 * BM * BK];  // 64 KB

    const int tid  = threadIdx.x;
    const int lane = tid & 63;
    const int w    = tid >> 6;       // wave 0..7
    const int wm   = w >> 2;         // 0..1  (M half)
    const int wn   = w & 3;          // 0..3  (N quarter)

    // T1: 512 blocks = 8 n-tiles x 64 m-tiles; XCD k owns n-column k.
    const int bid = blockIdx.x;
    const int wg  = (bid & 7) * 64 + (bid >> 3);
    const int n0  = (wg >> 6) * BN;
    const int m0  = (wg & 63) * BM;

    const int srow = tid >> 3;                        // LDS row (mod 64) this thread fills
    const int scol = ((tid & 7) ^ (srow & 7)) * 8;    // T2: inverse-swizzled global col
    const int fr   = lane & 15;
    const int fq   = lane >> 4;

    f32x4 acc[8][4] = {};

    auto STAGE = [&](int buf, int ks) {
        #pragma unroll
        for (int i = 0; i < 4; ++i) {
            const unsigned short* ga = xb + (uint64_t)(m0 + i * 64 + srow) * D_MODEL + ks + scol;
            __builtin_amdgcn_global_load_lds((as1_void*)(void*)ga,
                (as3_void*)(void*)&As[buf * (BM * BK) + i * 4096 + w * 512], 16, 0, 0);
        }
        #pragma unroll
        for (int i = 0; i < 4; ++i) {
            const unsigned short* gb = wt + (uint64_t)(n0 + i * 64 + srow) * D_MODEL + ks + scol;
            __builtin_amdgcn_global_load_lds((as1_void*)(void*)gb,
                (as3_void*)(void*)&Bs[buf * (BM * BK) + i * 4096 + w * 512], 16, 0, 0);
        }
    };

    STAGE(0, 0);
    __syncthreads();

    for (int t = 0; t < NT; ++t) {
        const int cur = t & 1;
        if (t + 1 < NT) STAGE(1 - cur, (t + 1) * BK);   // issue-first prefetch

        const unsigned short* Ab = &As[cur * (BM * BK)];
        const unsigned short* Bb = &Bs[cur * (BM * BK)];
        #pragma unroll
        for (int kk = 0; kk < BK; kk += 32) {
            const int slot = (kk >> 3) + fq;            // global k-octet
            bf16x8 b[4];
            #pragma unroll
            for (int n = 0; n < 4; n++) {
                const int rb = wn * 64 + n * 16 + fr;
                b[n] = *reinterpret_cast<const bf16x8*>(&Bb[rb * 64 + ((slot ^ (fr & 7)) * 8)]);
            }
            #pragma unroll
            for (int m = 0; m < 8; m++) {
                const int ra = wm * 128 + m * 16 + fr;
                bf16x8 a = *reinterpret_cast<const bf16x8*>(&Ab[ra * 64 + ((slot ^ (fr & 7)) * 8)]);
                #pragma unroll
                for (int n = 0; n < 4; n++)
                    acc[m][n] = __builtin_amdgcn_mfma_f32_16x16x32_bf16(a, b[n], acc[m][n], 0, 0, 0);
            }
        }
        __syncthreads();
    }

    // epilogue: D layout col=lane&15, row=(lane>>4)*4+reg  [verified m89/m91]
    #pragma unroll
    for (int m = 0; m < 8; m++) {
        const int grow = m0 + wm * 128 + m * 16 + fq * 4;
        #pragma unroll
        for (int n = 0; n < 4; n++) {
            const int gcol = n0 + wn * 64 + n * 16 + fr;
            const float bv = bias[gcol];
            #pragma unroll
            for (int r = 0; r < 4; r++) {
                projb[(uint64_t)(grow + r) * NPROJ + gcol] = f2bf(acc[m][n][r] + bv);
            }
        }
    }
}

// ---------------- K2: streaming RoPE(on-the-fly trig) + conv7 + SiLU + gate + RMSNorm ----------------
// cos/sin computed in-register: angle = t * invf, invf = 10000^(-c/512).
// Kills the ~67MB effective cos/sin table traffic that made every table-based
// variant (R3/R7/R8/R9) ~30us slower than the no-rope post (R5).
__global__ __launch_bounds__(512) void k_post(const unsigned short* __restrict__ projb,
                                              const float* __restrict__ kw,
                                              const float* __restrict__ dwb,
                                              const float* __restrict__ gamma,
                                              float* __restrict__ out) {
    const int blk  = blockIdx.x;
    const int b    = blk / (T_LEN / CHUNK);
    const int t0   = (blk % (T_LEN / CHUNK)) * CHUNK;
    const int c    = threadIdx.x;          // rope pair index 0..511
    const int d0   = c * 2;
    const uint64_t bbase = (uint64_t)b * T_LEN;

    // invf = 10000^(-c/512) = 2^(-c * log2(10000) / 512)
    const float invf = exp2f((float)c * (-13.287712379549449f / 512.0f));

    float kwv[7][2];
    #pragma unroll
    for (int j = 0; j < 7; j++) {
        kwv[j][0] = kw[j * D_MODEL + d0];
        kwv[j][1] = kw[j * D_MODEL + d0 + 1];
    }
    const float bv0 = dwb[d0], bv1 = dwb[d0 + 1];
    const float gm0 = gamma[d0], gm1 = gamma[d0 + 1];

    __shared__ float red[2][8];

    auto load_rope = [&](int tj, float& o0, float& o1) {
        if ((unsigned)tj < (unsigned)T_LEN) {
            ushort2 u = *reinterpret_cast<const ushort2*>(projb + (bbase + tj) * NPROJ + d0);
            float sv, cv;
            __sincosf((float)tj * invf, &sv, &cv);
            float x0 = bf2f(u.x), x1 = bf2f(u.y);
            o0 = x0 * cv - x1 * sv;
            o1 = x0 * sv + x1 * cv;
        } else { o0 = 0.f; o1 = 0.f; }
    };

    float rg[6][2];
    #pragma unroll
    for (int j = 0; j < 6; j++) load_rope(t0 - 3 + j, rg[j][0], rg[j][1]);
    float nx0, nx1;
    load_rope(t0 + 3, nx0, nx1);

    ushort2 xb_cur = *reinterpret_cast<const ushort2*>(projb + (bbase + t0) * NPROJ + D_MODEL + d0);

    for (int t = t0; t < t0 + CHUNK; ++t) {
        const float r60 = nx0, r61 = nx1;

        float acc0 = rg[0][0] * kwv[0][0] + rg[1][0] * kwv[1][0] + rg[2][0] * kwv[2][0]
                   + rg[3][0] * kwv[3][0] + rg[4][0] * kwv[4][0] + rg[5][0] * kwv[5][0]
                   + r60 * kwv[6][0] + bv0;
        float acc1 = rg[0][1] * kwv[0][1] + rg[1][1] * kwv[1][1] + rg[2][1] * kwv[2][1]
                   + rg[3][1] * kwv[3][1] + rg[4][1] * kwv[4][1] + rg[5][1] * kwv[5][1]
                   + r61 * kwv[6][1] + bv1;

        load_rope(t + 4, nx0, nx1);
        const ushort2 xb_use = xb_cur;
        if (t + 1 < t0 + CHUNK) {
            xb_cur = *reinterpret_cast<const ushort2*>(projb + (bbase + t + 1) * NPROJ + D_MODEL + d0);
        }

        // SiLU(conv) * sigmoid(x_b)
        float a0 = acc0 * sigmoidf(acc0);
        float a1 = acc1 * sigmoidf(acc1);
        float g0 = a0 * sigmoidf(bf2f(xb_use.x));
        float g1 = a1 * sigmoidf(bf2f(xb_use.y));

        float ssq = g0 * g0 + g1 * g1;
        #pragma unroll
        for (int off = 32; off; off >>= 1) ssq += __shfl_down(ssq, off);
        const int p = t & 1;
        if ((threadIdx.x & 63) == 0) red[p][threadIdx.x >> 6] = ssq;
        __syncthreads();
        float total = red[p][0] + red[p][1] + red[p][2] + red[p][3]
                    + red[p][4] + red[p][5] + red[p][6] + red[p][7];
        const float inv = 1.0f / sqrtf(total * (1.0f / (float)D_MODEL) + 1e-8f);

        float2 o;
        o.x = g0 * inv * gm0;
        o.y = g1 * inv * gm1;
        *reinterpret_cast<float2*>(out + (bbase + t) * D_MODEL + d0) = o;

        #pragma unroll
        for (int j = 0; j < 5; j++) { rg[j][0] = rg[j + 1][0]; rg[j][1] = rg[j + 1][1]; }
        rg[5][0] = r60; rg[5][1] = r61;
    }
}

extern "C" void kernel_launch(void* const* d_in, const int* in_sizes, int n_in,
                              void* d_out, int out_size, void* d_ws, size_t ws_size,
                              hipStream_t stream) {
    const float* x     = (const float*)d_in[0];
    const float* sinp  = (const float*)d_in[1];   // unused: trig computed on the fly
    const float* cosp  = (const float*)d_in[2];   // unused
    const float* W     = (const float*)d_in[3];
    const float* bproj = (const float*)d_in[4];
    const float* dwk   = (const float*)d_in[5];
    const float* dwb   = (const float*)d_in[6];
    const float* gamma = (const float*)d_in[7];
    float* out = (float*)d_out;
    (void)sinp; (void)cosp;

    unsigned short* xb    = (unsigned short*)d_ws;                       // 32 MB
    unsigned short* wt    = xb + (size_t)NROWS * D_MODEL;                // 4 MB
    unsigned short* projb = wt + (size_t)NPROJ * D_MODEL;                // 64 MB

    const int cvt_x_blocks = (NROWS * D_MODEL) / (256 * 4);              // 16384
    const int cvt_w_blocks = (NPROJ / 32) * (D_MODEL / 32);              // 2048
    k_cvt<<<cvt_x_blocks + cvt_w_blocks, 256, 0, stream>>>(x, xb, W, wt);
    k_gemm<<<(NPROJ / BN) * (NROWS / BM), 512, 0, stream>>>(xb, wt, bproj, projb);
    k_post<<<B_SZ * (T_LEN / CHUNK), 512, 0, stream>>>(projb, dwk, dwb, gamma, out);
}

// Round 11
// 147.612 us; speedup vs baseline: 1.0415x; 1.0415x over previous
//
#include <hip/hip_runtime.h>
#include <stdint.h>

#define D_MODEL 1024
#define T_LEN   4096
#define B_SZ    4
#define NROWS   (B_SZ * T_LEN)   // 16384
#define NPROJ   (2 * D_MODEL)    // 2048
#define CHUNK   16               // rows of T per k_post block (2 barriers total)

#define BM 256
#define BN 256
#define BK 64
#define NT (D_MODEL / BK)        // 16 K-steps

typedef __attribute__((ext_vector_type(8))) __bf16 bf16x8;
typedef __attribute__((ext_vector_type(4))) float  f32x4;

using as1_void = __attribute__((address_space(1))) void;
using as3_void = __attribute__((address_space(3))) void;

__device__ inline float bf2f(unsigned short u) {
    union { unsigned int i; float f; } v; v.i = ((unsigned int)u) << 16; return v.f;
}
__device__ inline unsigned short f2bf(float f) {
    union { float f; unsigned int i; } v; v.f = f;
    return (unsigned short)((v.i + 0x7fffu + ((v.i >> 16) & 1u)) >> 16);
}
__device__ inline float sigmoidf(float x) { return 1.0f / (1.0f + __expf(-x)); }

// ---------------- K0: fused converts (x fp32->bf16, W fp32->bf16 transposed) ----------------
__global__ __launch_bounds__(256) void k_cvt(const float* __restrict__ x,
                                             unsigned short* __restrict__ xb,
                                             const float* __restrict__ W,
                                             unsigned short* __restrict__ wt) {
    __shared__ unsigned short tile[32][33];
    int bid = blockIdx.x;
    if (bid < (NROWS * D_MODEL) / (256 * 4)) {
        int i = (bid * 256 + threadIdx.x) * 4;
        float4 v = *reinterpret_cast<const float4*>(x + i);
        ushort4 o;
        o.x = f2bf(v.x); o.y = f2bf(v.y); o.z = f2bf(v.z); o.w = f2bf(v.w);
        *reinterpret_cast<ushort4*>(xb + i) = o;
    } else {
        bid -= (NROWS * D_MODEL) / (256 * 4);
        int n0 = (bid & 63) * 32, k0 = (bid >> 6) * 32;
        int c = threadIdx.x & 31, r = threadIdx.x >> 5;  // r in 0..7
        #pragma unroll
        for (int i = 0; i < 4; i++) {
            int kk = r + i * 8;
            tile[kk][c] = f2bf(W[(uint64_t)(k0 + kk) * NPROJ + n0 + c]);
        }
        __syncthreads();
        #pragma unroll
        for (int i = 0; i < 4; i++) {
            int nn = r + i * 8;
            wt[(uint64_t)(n0 + nn) * D_MODEL + k0 + c] = tile[c][nn];
        }
    }
}

// ---------------- K1: GEMM proj = xb @ wt^T + bias, store bf16 ----------------
// EXACT R3 kernel (verified 85.5us x6 runs, 0 bank conflicts). DO NOT touch
// the epilogue: any branch/extra math there perturbs the K-loop schedule
// (R5: +31us, R6: +14us).
__global__ __launch_bounds__(512, 2) void k_gemm(const unsigned short* __restrict__ xb,
                                                 const unsigned short* __restrict__ wt,
                                                 const float* __restrict__ bias,
                                                 unsigned short* __restrict__ projb) {
    __shared__ __align__(16) unsigned short As[2 * BM * BK];  // 64 KB
    __shared__ __align__(16) unsigned short Bs[2 * BM * BK];  // 64 KB

    const int tid  = threadIdx.x;
    const int lane = tid & 63;
    const int w    = tid >> 6;       // wave 0..7
    const int wm   = w >> 2;         // 0..1  (M half)
    const int wn   = w & 3;          // 0..3  (N quarter)

    // T1: 512 blocks = 8 n-tiles x 64 m-tiles; XCD k owns n-column k.
    const int bid = blockIdx.x;
    const int wg  = (bid & 7) * 64 + (bid >> 3);
    const int n0  = (wg >> 6) * BN;
    const int m0  = (wg & 63) * BM;

    const int srow = tid >> 3;                        // LDS row (mod 64) this thread fills
    const int scol = ((tid & 7) ^ (srow & 7)) * 8;    // T2: inverse-swizzled global col
    const int fr   = lane & 15;
    const int fq   = lane >> 4;

    f32x4 acc[8][4] = {};

    auto STAGE = [&](int buf, int ks) {
        #pragma unroll
        for (int i = 0; i < 4; ++i) {
            const unsigned short* ga = xb + (uint64_t)(m0 + i * 64 + srow) * D_MODEL + ks + scol;
            __builtin_amdgcn_global_load_lds((as1_void*)(void*)ga,
                (as3_void*)(void*)&As[buf * (BM * BK) + i * 4096 + w * 512], 16, 0, 0);
        }
        #pragma unroll
        for (int i = 0; i < 4; ++i) {
            const unsigned short* gb = wt + (uint64_t)(n0 + i * 64 + srow) * D_MODEL + ks + scol;
            __builtin_amdgcn_global_load_lds((as1_void*)(void*)gb,
                (as3_void*)(void*)&Bs[buf * (BM * BK) + i * 4096 + w * 512], 16, 0, 0);
        }
    };

    STAGE(0, 0);
    __syncthreads();

    for (int t = 0; t < NT; ++t) {
        const int cur = t & 1;
        if (t + 1 < NT) STAGE(1 - cur, (t + 1) * BK);   // issue-first prefetch

        const unsigned short* Ab = &As[cur * (BM * BK)];
        const unsigned short* Bb = &Bs[cur * (BM * BK)];
        #pragma unroll
        for (int kk = 0; kk < BK; kk += 32) {
            const int slot = (kk >> 3) + fq;            // global k-octet
            bf16x8 b[4];
            #pragma unroll
            for (int n = 0; n < 4; n++) {
                const int rb = wn * 64 + n * 16 + fr;
                b[n] = *reinterpret_cast<const bf16x8*>(&Bb[rb * 64 + ((slot ^ (fr & 7)) * 8)]);
            }
            #pragma unroll
            for (int m = 0; m < 8; m++) {
                const int ra = wm * 128 + m * 16 + fr;
                bf16x8 a = *reinterpret_cast<const bf16x8*>(&Ab[ra * 64 + ((slot ^ (fr & 7)) * 8)]);
                #pragma unroll
                for (int n = 0; n < 4; n++)
                    acc[m][n] = __builtin_amdgcn_mfma_f32_16x16x32_bf16(a, b[n], acc[m][n], 0, 0, 0);
            }
        }
        __syncthreads();
    }

    // epilogue: D layout col=lane&15, row=(lane>>4)*4+reg  [verified m89/m91]
    #pragma unroll
    for (int m = 0; m < 8; m++) {
        const int grow = m0 + wm * 128 + m * 16 + fq * 4;
        #pragma unroll
        for (int n = 0; n < 4; n++) {
            const int gcol = n0 + wn * 64 + n * 16 + fr;
            const float bv = bias[gcol];
            #pragma unroll
            for (int r = 0; r < 4; r++) {
                projb[(uint64_t)(grow + r) * NPROJ + gcol] = f2bf(acc[m][n][r] + bv);
            }
        }
    }
}

// ---------------- K2: two-phase RoPE + conv7 + SiLU + gate + RMSNorm ----------------
// Phase 1: CHUNK rows computed with ZERO barriers (wave-level shfl reduce +
// ds_write of partials; g kept in registers, statically indexed via full
// unroll). ONE barrier. Fold partials -> inv[row]. ONE barrier. Phase 2:
// scale+store all rows. Removes the per-row vmcnt-draining __syncthreads
// that serialized every previous variant (R3/R7/R9/R10 all ~50us).
__global__ __launch_bounds__(512) void k_post(const unsigned short* __restrict__ projb,
                                              const float* __restrict__ kw,
                                              const float* __restrict__ dwb,
                                              const float* __restrict__ gamma,
                                              float* __restrict__ out) {
    const int blk  = blockIdx.x;
    const int b    = blk / (T_LEN / CHUNK);
    const int t0   = (blk % (T_LEN / CHUNK)) * CHUNK;
    const int c    = threadIdx.x;          // rope pair index 0..511
    const int d0   = c * 2;
    const uint64_t bbase = (uint64_t)b * T_LEN;

    // invf = 10000^(-c/512) = 2^(-c * log2(10000) / 512)
    const float invf = exp2f((float)c * (-13.287712379549449f / 512.0f));

    float kwv[7][2];
    #pragma unroll
    for (int j = 0; j < 7; j++) {
        kwv[j][0] = kw[j * D_MODEL + d0];
        kwv[j][1] = kw[j * D_MODEL + d0 + 1];
    }
    const float bv0 = dwb[d0], bv1 = dwb[d0 + 1];
    const float gm0 = gamma[d0], gm1 = gamma[d0 + 1];

    __shared__ float partial[CHUNK][8];
    __shared__ float invr[CHUNK];

    auto load_rope = [&](int tj, float& o0, float& o1) {
        if ((unsigned)tj < (unsigned)T_LEN) {
            ushort2 u = *reinterpret_cast<const ushort2*>(projb + (bbase + tj) * NPROJ + d0);
            float sv, cv;
            __sincosf((float)tj * invf, &sv, &cv);
            float x0 = bf2f(u.x), x1 = bf2f(u.y);
            o0 = x0 * cv - x1 * sv;
            o1 = x0 * sv + x1 * cv;
        } else { o0 = 0.f; o1 = 0.f; }
    };

    float rg[6][2];
    #pragma unroll
    for (int j = 0; j < 6; j++) load_rope(t0 - 3 + j, rg[j][0], rg[j][1]);

    float ga[CHUNK], gb[CHUNK];   // statically indexed after full unroll

    // ---- phase 1: no barriers ----
    #pragma unroll
    for (int r = 0; r < CHUNK; ++r) {
        float nx0, nx1;
        load_rope(t0 + r + 3, nx0, nx1);
        ushort2 xbv = *reinterpret_cast<const ushort2*>(
            projb + (bbase + t0 + r) * NPROJ + D_MODEL + d0);

        float acc0 = rg[0][0] * kwv[0][0] + rg[1][0] * kwv[1][0] + rg[2][0] * kwv[2][0]
                   + rg[3][0] * kwv[3][0] + rg[4][0] * kwv[4][0] + rg[5][0] * kwv[5][0]
                   + nx0 * kwv[6][0] + bv0;
        float acc1 = rg[0][1] * kwv[0][1] + rg[1][1] * kwv[1][1] + rg[2][1] * kwv[2][1]
                   + rg[3][1] * kwv[3][1] + rg[4][1] * kwv[4][1] + rg[5][1] * kwv[5][1]
                   + nx1 * kwv[6][1] + bv1;

        float a0 = acc0 * sigmoidf(acc0);
        float a1 = acc1 * sigmoidf(acc1);
        float g0 = a0 * sigmoidf(bf2f(xbv.x));
        float g1 = a1 * sigmoidf(bf2f(xbv.y));
        ga[r] = g0; gb[r] = g1;

        float ssq = g0 * g0 + g1 * g1;
        #pragma unroll
        for (int off = 32; off; off >>= 1) ssq += __shfl_down(ssq, off);
        if ((c & 63) == 0) partial[r][c >> 6] = ssq;

        #pragma unroll
        for (int j = 0; j < 5; j++) { rg[j][0] = rg[j + 1][0]; rg[j][1] = rg[j + 1][1]; }
        rg[5][0] = nx0; rg[5][1] = nx1;
    }

    __syncthreads();
    if (c < CHUNK) {
        float s = partial[c][0] + partial[c][1] + partial[c][2] + partial[c][3]
                + partial[c][4] + partial[c][5] + partial[c][6] + partial[c][7];
        invr[c] = 1.0f / sqrtf(s * (1.0f / (float)D_MODEL) + 1e-8f);
    }
    __syncthreads();

    // ---- phase 2: scale + store ----
    #pragma unroll
    for (int r = 0; r < CHUNK; ++r) {
        const float iv = invr[r];
        float2 o;
        o.x = ga[r] * iv * gm0;
        o.y = gb[r] * iv * gm1;
        *reinterpret_cast<float2*>(out + (bbase + t0 + r) * D_MODEL + d0) = o;
    }
}

extern "C" void kernel_launch(void* const* d_in, const int* in_sizes, int n_in,
                              void* d_out, int out_size, void* d_ws, size_t ws_size,
                              hipStream_t stream) {
    const float* x     = (const float*)d_in[0];
    const float* sinp  = (const float*)d_in[1];   // unused: trig computed on the fly
    const float* cosp  = (const float*)d_in[2];   // unused
    const float* W     = (const float*)d_in[3];
    const float* bproj = (const float*)d_in[4];
    const float* dwk   = (const float*)d_in[5];
    const float* dwb   = (const float*)d_in[6];
    const float* gamma = (const float*)d_in[7];
    float* out = (float*)d_out;
    (void)sinp; (void)cosp;

    unsigned short* xb    = (unsigned short*)d_ws;                       // 32 MB
    unsigned short* wt    = xb + (size_t)NROWS * D_MODEL;                // 4 MB
    unsigned short* projb = wt + (size_t)NPROJ * D_MODEL;                // 64 MB

    const int cvt_x_blocks = (NROWS * D_MODEL) / (256 * 4);              // 16384
    const int cvt_w_blocks = (NPROJ / 32) * (D_MODEL / 32);              // 2048
    k_cvt<<<cvt_x_blocks + cvt_w_blocks, 256, 0, stream>>>(x, xb, W, wt);
    k_gemm<<<(NPROJ / BN) * (NROWS / BM), 512, 0, stream>>>(xb, wt, bproj, projb);
    k_post<<<B_SZ * (T_LEN / CHUNK), 512, 0, stream>>>(projb, dwk, dwb, gamma, out);
}

// Round 12
// 135.290 us; speedup vs baseline: 1.1363x; 1.0911x over previous
//
#include <hip/hip_runtime.h>
#include <stdint.h>

#define D_MODEL 1024
#define T_LEN   4096
#define B_SZ    4
#define NROWS   (B_SZ * T_LEN)   // 16384
#define NPROJ   (2 * D_MODEL)    // 2048
#define CHUNK   8                // rows of T per k_post block

#define BM 256
#define BN 256
#define BK 64
#define NT (D_MODEL / BK)        // 16 K-steps

typedef __attribute__((ext_vector_type(8))) __bf16 bf16x8;
typedef __attribute__((ext_vector_type(4))) float  f32x4;

using as1_void = __attribute__((address_space(1))) void;
using as3_void = __attribute__((address_space(3))) void;

__device__ inline float bf2f(unsigned short u) {
    union { unsigned int i; float f; } v; v.i = ((unsigned int)u) << 16; return v.f;
}
__device__ inline unsigned short f2bf(float f) {
    union { float f; unsigned int i; } v; v.f = f;
    return (unsigned short)((v.i + 0x7fffu + ((v.i >> 16) & 1u)) >> 16);
}
__device__ inline unsigned int f2bf2(float lo, float hi) {
    return (unsigned int)f2bf(lo) | ((unsigned int)f2bf(hi) << 16);
}
__device__ inline float sigmoidf(float x) { return 1.0f / (1.0f + __expf(-x)); }

// ---------------- K0: fused converts (x fp32->bf16 8/thread, W fp32->bf16 transposed) ----------------
#define CVT_X_BLOCKS ((NROWS * D_MODEL) / (256 * 8))   // 8192
__global__ __launch_bounds__(256) void k_cvt(const float* __restrict__ x,
                                             unsigned short* __restrict__ xb,
                                             const float* __restrict__ W,
                                             unsigned short* __restrict__ wt) {
    __shared__ unsigned short tile[32][33];
    int bid = blockIdx.x;
    if (bid < CVT_X_BLOCKS) {
        int i = (bid * 256 + threadIdx.x) * 8;
        float4 v0 = *reinterpret_cast<const float4*>(x + i);
        float4 v1 = *reinterpret_cast<const float4*>(x + i + 4);
        uint4 o;
        o.x = f2bf2(v0.x, v0.y);
        o.y = f2bf2(v0.z, v0.w);
        o.z = f2bf2(v1.x, v1.y);
        o.w = f2bf2(v1.z, v1.w);
        *reinterpret_cast<uint4*>(xb + i) = o;
    } else {
        bid -= CVT_X_BLOCKS;
        int n0 = (bid & 63) * 32, k0 = (bid >> 6) * 32;
        int c = threadIdx.x & 31, r = threadIdx.x >> 5;  // r in 0..7
        #pragma unroll
        for (int i = 0; i < 4; i++) {
            int kk = r + i * 8;
            tile[kk][c] = f2bf(W[(uint64_t)(k0 + kk) * NPROJ + n0 + c]);
        }
        __syncthreads();
        #pragma unroll
        for (int i = 0; i < 4; i++) {
            int nn = r + i * 8;
            wt[(uint64_t)(n0 + nn) * D_MODEL + k0 + c] = tile[c][nn];
        }
    }
}

// ---------------- K1: GEMM proj = xb @ wt^T + bias, store bf16 ----------------
// EXACT R3 kernel (verified 85.5us x7 runs, 0 bank conflicts). DO NOT touch.
__global__ __launch_bounds__(512, 2) void k_gemm(const unsigned short* __restrict__ xb,
                                                 const unsigned short* __restrict__ wt,
                                                 const float* __restrict__ bias,
                                                 unsigned short* __restrict__ projb) {
    __shared__ __align__(16) unsigned short As[2 * BM * BK];  // 64 KB
    __shared__ __align__(16) unsigned short Bs[2 * BM * BK];  // 64 KB

    const int tid  = threadIdx.x;
    const int lane = tid & 63;
    const int w    = tid >> 6;       // wave 0..7
    const int wm   = w >> 2;         // 0..1  (M half)
    const int wn   = w & 3;          // 0..3  (N quarter)

    const int bid = blockIdx.x;
    const int wg  = (bid & 7) * 64 + (bid >> 3);
    const int n0  = (wg >> 6) * BN;
    const int m0  = (wg & 63) * BM;

    const int srow = tid >> 3;
    const int scol = ((tid & 7) ^ (srow & 7)) * 8;
    const int fr   = lane & 15;
    const int fq   = lane >> 4;

    f32x4 acc[8][4] = {};

    auto STAGE = [&](int buf, int ks) {
        #pragma unroll
        for (int i = 0; i < 4; ++i) {
            const unsigned short* ga = xb + (uint64_t)(m0 + i * 64 + srow) * D_MODEL + ks + scol;
            __builtin_amdgcn_global_load_lds((as1_void*)(void*)ga,
                (as3_void*)(void*)&As[buf * (BM * BK) + i * 4096 + w * 512], 16, 0, 0);
        }
        #pragma unroll
        for (int i = 0; i < 4; ++i) {
            const unsigned short* gb = wt + (uint64_t)(n0 + i * 64 + srow) * D_MODEL + ks + scol;
            __builtin_amdgcn_global_load_lds((as1_void*)(void*)gb,
                (as3_void*)(void*)&Bs[buf * (BM * BK) + i * 4096 + w * 512], 16, 0, 0);
        }
    };

    STAGE(0, 0);
    __syncthreads();

    for (int t = 0; t < NT; ++t) {
        const int cur = t & 1;
        if (t + 1 < NT) STAGE(1 - cur, (t + 1) * BK);

        const unsigned short* Ab = &As[cur * (BM * BK)];
        const unsigned short* Bb = &Bs[cur * (BM * BK)];
        #pragma unroll
        for (int kk = 0; kk < BK; kk += 32) {
            const int slot = (kk >> 3) + fq;
            bf16x8 b[4];
            #pragma unroll
            for (int n = 0; n < 4; n++) {
                const int rb = wn * 64 + n * 16 + fr;
                b[n] = *reinterpret_cast<const bf16x8*>(&Bb[rb * 64 + ((slot ^ (fr & 7)) * 8)]);
            }
            #pragma unroll
            for (int m = 0; m < 8; m++) {
                const int ra = wm * 128 + m * 16 + fr;
                bf16x8 a = *reinterpret_cast<const bf16x8*>(&Ab[ra * 64 + ((slot ^ (fr & 7)) * 8)]);
                #pragma unroll
                for (int n = 0; n < 4; n++)
                    acc[m][n] = __builtin_amdgcn_mfma_f32_16x16x32_bf16(a, b[n], acc[m][n], 0, 0, 0);
            }
        }
        __syncthreads();
    }

    #pragma unroll
    for (int m = 0; m < 8; m++) {
        const int grow = m0 + wm * 128 + m * 16 + fq * 4;
        #pragma unroll
        for (int n = 0; n < 4; n++) {
            const int gcol = n0 + wn * 64 + n * 16 + fr;
            const float bv = bias[gcol];
            #pragma unroll
            for (int r = 0; r < 4; r++) {
                projb[(uint64_t)(grow + r) * NPROJ + gcol] = f2bf(acc[m][n][r] + bv);
            }
        }
    }
}

// ---------------- K2: batched-load two-phase RoPE + conv7 + SiLU + gate + RMSNorm ----------------
// All 15 tap + 8 x_b loads issued up front (unconditional, clamped addr,
// value zeroed by select) -> max memory-level parallelism. Incremental trig
// (2 sincos total/thread). CHUNK=8 keeps VGPR ~100 -> 2 blocks/CU.
__global__ __launch_bounds__(512) void k_post(const unsigned short* __restrict__ projb,
                                              const float* __restrict__ kw,
                                              const float* __restrict__ dwb,
                                              const float* __restrict__ gamma,
                                              float* __restrict__ out) {
    const int blk  = blockIdx.x;
    const int b    = blk / (T_LEN / CHUNK);
    const int t0   = (blk % (T_LEN / CHUNK)) * CHUNK;
    const int c    = threadIdx.x;          // rope pair index 0..511
    const int d0   = c * 2;
    const uint64_t bbase = (uint64_t)b * T_LEN;

    // ---- batched loads: 15 taps + 8 x_b, all issued before any use ----
    unsigned int tap[CHUNK + 7];
    unsigned int xbv[CHUNK];
    #pragma unroll
    for (int i = 0; i < CHUNK + 7; ++i) {
        int tj = t0 - 3 + i;
        int ta = tj < 0 ? 0 : (tj >= T_LEN ? T_LEN - 1 : tj);
        tap[i] = *reinterpret_cast<const unsigned int*>(projb + (bbase + ta) * NPROJ + d0);
    }
    #pragma unroll
    for (int r = 0; r < CHUNK; ++r) {
        xbv[r] = *reinterpret_cast<const unsigned int*>(projb + (bbase + t0 + r) * NPROJ + D_MODEL + d0);
    }

    // invf = 10000^(-c/512); trig at t0-3 then incremental rotation per tap
    const float invf = exp2f((float)c * (-13.287712379549449f / 512.0f));
    float sn, cs, sF, cF;
    __sincosf((float)(t0 - 3) * invf, &sn, &cs);
    __sincosf(invf, &sF, &cF);

    float kwv[7][2];
    #pragma unroll
    for (int j = 0; j < 7; j++) {
        kwv[j][0] = kw[j * D_MODEL + d0];
        kwv[j][1] = kw[j * D_MODEL + d0 + 1];
    }
    const float bv0 = dwb[d0], bv1 = dwb[d0 + 1];
    const float gm0 = gamma[d0], gm1 = gamma[d0 + 1];

    __shared__ float partial[CHUNK][8];
    __shared__ float invr[CHUNK];

    // ---- rope all taps (register-only after loads) ----
    float rx[CHUNK + 7][2];
    #pragma unroll
    for (int i = 0; i < CHUNK + 7; ++i) {
        const int tj = t0 - 3 + i;
        const bool valid = (unsigned)tj < (unsigned)T_LEN;
        float x0 = bf2f((unsigned short)(tap[i] & 0xffffu));
        float x1 = bf2f((unsigned short)(tap[i] >> 16));
        float r0 = x0 * cs - x1 * sn;
        float r1 = x0 * sn + x1 * cs;
        rx[i][0] = valid ? r0 : 0.f;
        rx[i][1] = valid ? r1 : 0.f;
        float c2 = cs * cF - sn * sF;      // advance angle by invf
        sn = sn * cF + cs * sF;
        cs = c2;
    }

    // ---- conv + SiLU + gate + wave-reduce (no barriers) ----
    float ga[CHUNK], gb[CHUNK];
    #pragma unroll
    for (int r = 0; r < CHUNK; ++r) {
        float acc0 = bv0, acc1 = bv1;
        #pragma unroll
        for (int j = 0; j < 7; j++) {
            acc0 += rx[r + j][0] * kwv[j][0];
            acc1 += rx[r + j][1] * kwv[j][1];
        }
        float a0 = acc0 * sigmoidf(acc0);
        float a1 = acc1 * sigmoidf(acc1);
        float g0 = a0 * sigmoidf(bf2f((unsigned short)(xbv[r] & 0xffffu)));
        float g1 = a1 * sigmoidf(bf2f((unsigned short)(xbv[r] >> 16)));
        ga[r] = g0; gb[r] = g1;

        float ssq = g0 * g0 + g1 * g1;
        #pragma unroll
        for (int off = 32; off; off >>= 1) ssq += __shfl_down(ssq, off);
        if ((c & 63) == 0) partial[r][c >> 6] = ssq;
    }

    __syncthreads();
    if (c < CHUNK) {
        float s = partial[c][0] + partial[c][1] + partial[c][2] + partial[c][3]
                + partial[c][4] + partial[c][5] + partial[c][6] + partial[c][7];
        invr[c] = 1.0f / sqrtf(s * (1.0f / (float)D_MODEL) + 1e-8f);
    }
    __syncthreads();

    #pragma unroll
    for (int r = 0; r < CHUNK; ++r) {
        const float iv = invr[r];
        float2 o;
        o.x = ga[r] * iv * gm0;
        o.y = gb[r] * iv * gm1;
        *reinterpret_cast<float2*>(out + (bbase + t0 + r) * D_MODEL + d0) = o;
    }
}

extern "C" void kernel_launch(void* const* d_in, const int* in_sizes, int n_in,
                              void* d_out, int out_size, void* d_ws, size_t ws_size,
                              hipStream_t stream) {
    const float* x     = (const float*)d_in[0];
    const float* sinp  = (const float*)d_in[1];   // unused: trig computed on the fly
    const float* cosp  = (const float*)d_in[2];   // unused
    const float* W     = (const float*)d_in[3];
    const float* bproj = (const float*)d_in[4];
    const float* dwk   = (const float*)d_in[5];
    const float* dwb   = (const float*)d_in[6];
    const float* gamma = (const float*)d_in[7];
    float* out = (float*)d_out;
    (void)sinp; (void)cosp;

    unsigned short* xb    = (unsigned short*)d_ws;                       // 32 MB
    unsigned short* wt    = xb + (size_t)NROWS * D_MODEL;                // 4 MB
    unsigned short* projb = wt + (size_t)NPROJ * D_MODEL;                // 64 MB

    const int cvt_w_blocks = (NPROJ / 32) * (D_MODEL / 32);              // 2048
    k_cvt<<<CVT_X_BLOCKS + cvt_w_blocks, 256, 0, stream>>>(x, xb, W, wt);
    k_gemm<<<(NPROJ / BN) * (NROWS / BM), 512, 0, stream>>>(xb, wt, bproj, projb);
    k_post<<<B_SZ * (T_LEN / CHUNK), 512, 0, stream>>>(projb, dwk, dwb, gamma, out);
}

// Round 13
// 134.710 us; speedup vs baseline: 1.1412x; 1.0043x over previous
//
#include <hip/hip_runtime.h>
#include <stdint.h>

#define D_MODEL 1024
#define T_LEN   4096
#define B_SZ    4
#define NROWS   (B_SZ * T_LEN)   // 16384
#define NPROJ   (2 * D_MODEL)    // 2048
#define CHUNK   8                // rows of T per k_post block

#define BM 256
#define BN 256
#define BK 64
#define NT (D_MODEL / BK)        // 16 K-steps

typedef __attribute__((ext_vector_type(8))) __bf16 bf16x8;
typedef __attribute__((ext_vector_type(4))) float  f32x4;

using as1_void = __attribute__((address_space(1))) void;
using as3_void = __attribute__((address_space(3))) void;

__device__ inline float bf2f(unsigned short u) {
    union { unsigned int i; float f; } v; v.i = ((unsigned int)u) << 16; return v.f;
}
__device__ inline unsigned short f2bf(float f) {
    union { float f; unsigned int i; } v; v.f = f;
    return (unsigned short)((v.i + 0x7fffu + ((v.i >> 16) & 1u)) >> 16);
}
__device__ inline unsigned int f2bf2(float lo, float hi) {
    return (unsigned int)f2bf(lo) | ((unsigned int)f2bf(hi) << 16);
}
__device__ inline float sigmoidf(float x) { return 1.0f / (1.0f + __expf(-x)); }

// ---------------- K0: fused converts (x fp32->bf16 8/thread, W fp32->bf16 transposed) ----------------
#define CVT_X_BLOCKS ((NROWS * D_MODEL) / (256 * 8))   // 8192
__global__ __launch_bounds__(256) void k_cvt(const float* __restrict__ x,
                                             unsigned short* __restrict__ xb,
                                             const float* __restrict__ W,
                                             unsigned short* __restrict__ wt) {
    __shared__ unsigned short tile[32][33];
    int bid = blockIdx.x;
    if (bid < CVT_X_BLOCKS) {
        int i = (bid * 256 + threadIdx.x) * 8;
        float4 v0 = *reinterpret_cast<const float4*>(x + i);
        float4 v1 = *reinterpret_cast<const float4*>(x + i + 4);
        uint4 o;
        o.x = f2bf2(v0.x, v0.y);
        o.y = f2bf2(v0.z, v0.w);
        o.z = f2bf2(v1.x, v1.y);
        o.w = f2bf2(v1.z, v1.w);
        *reinterpret_cast<uint4*>(xb + i) = o;
    } else {
        bid -= CVT_X_BLOCKS;
        int n0 = (bid & 63) * 32, k0 = (bid >> 6) * 32;
        int c = threadIdx.x & 31, r = threadIdx.x >> 5;  // r in 0..7
        #pragma unroll
        for (int i = 0; i < 4; i++) {
            int kk = r + i * 8;
            tile[kk][c] = f2bf(W[(uint64_t)(k0 + kk) * NPROJ + n0 + c]);
        }
        __syncthreads();
        #pragma unroll
        for (int i = 0; i < 4; i++) {
            int nn = r + i * 8;
            wt[(uint64_t)(n0 + nn) * D_MODEL + k0 + c] = tile[c][nn];
        }
    }
}

// ---------------- K1: GEMM proj = xb @ wt^T + bias, store bf16 ----------------
// Same verified template (T1 block swizzle, T2 LDS swizzle, issue-first dbuf,
// one barrier/step) but 16 waves (1024 thr), per-wave 64x64 output:
// acc 128->64 VGPR -> 4 waves/SIMD instead of 2 -> compute-phase latency hiding.
__global__ __launch_bounds__(1024, 4) void k_gemm(const unsigned short* __restrict__ xb,
                                                  const unsigned short* __restrict__ wt,
                                                  const float* __restrict__ bias,
                                                  unsigned short* __restrict__ projb) {
    __shared__ __align__(16) unsigned short As[2 * BM * BK];  // 64 KB
    __shared__ __align__(16) unsigned short Bs[2 * BM * BK];  // 64 KB

    const int tid  = threadIdx.x;
    const int lane = tid & 63;
    const int w    = tid >> 6;       // wave 0..15
    const int wm   = w >> 2;         // 0..3  (M quarter)
    const int wn   = w & 3;          // 0..3  (N quarter)

    // T1: 512 blocks = 8 n-tiles x 64 m-tiles; XCD k owns n-column k.
    const int bid = blockIdx.x;
    const int wg  = (bid & 7) * 64 + (bid >> 3);
    const int n0  = (wg >> 6) * BN;
    const int m0  = (wg & 63) * BM;

    const int srow = tid >> 3;                        // 0..127 (LDS row this thread fills)
    const int scol = ((tid & 7) ^ (srow & 7)) * 8;    // T2 inverse-swizzled source octet
    const int fr   = lane & 15;
    const int fq   = lane >> 4;

    f32x4 acc[4][4] = {};

    auto STAGE = [&](int buf, int ks) {
        #pragma unroll
        for (int i = 0; i < 2; ++i) {
            const unsigned short* ga = xb + (uint64_t)(m0 + i * 128 + srow) * D_MODEL + ks + scol;
            __builtin_amdgcn_global_load_lds((as1_void*)(void*)ga,
                (as3_void*)(void*)&As[buf * (BM * BK) + i * 8192 + w * 512], 16, 0, 0);
        }
        #pragma unroll
        for (int i = 0; i < 2; ++i) {
            const unsigned short* gb = wt + (uint64_t)(n0 + i * 128 + srow) * D_MODEL + ks + scol;
            __builtin_amdgcn_global_load_lds((as1_void*)(void*)gb,
                (as3_void*)(void*)&Bs[buf * (BM * BK) + i * 8192 + w * 512], 16, 0, 0);
        }
    };

    STAGE(0, 0);
    __syncthreads();

    for (int t = 0; t < NT; ++t) {
        const int cur = t & 1;
        if (t + 1 < NT) STAGE(1 - cur, (t + 1) * BK);   // issue-first prefetch

        const unsigned short* Ab = &As[cur * (BM * BK)];
        const unsigned short* Bb = &Bs[cur * (BM * BK)];
        #pragma unroll
        for (int kk = 0; kk < BK; kk += 32) {
            const int slot = (kk >> 3) + fq;            // global k-octet
            bf16x8 b[4], a[4];
            #pragma unroll
            for (int n = 0; n < 4; n++) {
                const int rb = wn * 64 + n * 16 + fr;
                b[n] = *reinterpret_cast<const bf16x8*>(&Bb[rb * 64 + ((slot ^ (fr & 7)) * 8)]);
            }
            #pragma unroll
            for (int m = 0; m < 4; m++) {
                const int ra = wm * 64 + m * 16 + fr;
                a[m] = *reinterpret_cast<const bf16x8*>(&Ab[ra * 64 + ((slot ^ (fr & 7)) * 8)]);
            }
            #pragma unroll
            for (int m = 0; m < 4; m++)
                #pragma unroll
                for (int n = 0; n < 4; n++)
                    acc[m][n] = __builtin_amdgcn_mfma_f32_16x16x32_bf16(a[m], b[n], acc[m][n], 0, 0, 0);
        }
        __syncthreads();
    }

    // epilogue: D layout col=lane&15, row=(lane>>4)*4+reg  [verified m89/m91]
    #pragma unroll
    for (int m = 0; m < 4; m++) {
        const int grow = m0 + wm * 64 + m * 16 + fq * 4;
        #pragma unroll
        for (int n = 0; n < 4; n++) {
            const int gcol = n0 + wn * 64 + n * 16 + fr;
            const float bv = bias[gcol];
            #pragma unroll
            for (int r = 0; r < 4; r++) {
                projb[(uint64_t)(grow + r) * NPROJ + gcol] = f2bf(acc[m][n][r] + bv);
            }
        }
    }
}

// ---------------- K2: batched-load two-phase RoPE + conv7 + SiLU + gate + RMSNorm ----------------
// R12 structure (135.3us total) + T1 XCD swizzle: neighbor t-chunks share an
// XCD so the 7-row halo re-read hits L2 instead of HBM.
__global__ __launch_bounds__(512) void k_post(const unsigned short* __restrict__ projb,
                                              const float* __restrict__ kw,
                                              const float* __restrict__ dwb,
                                              const float* __restrict__ gamma,
                                              float* __restrict__ out) {
    // bijective XCD swizzle: 2048 blocks, 256 contiguous chunks per XCD
    const int xcd = blockIdx.x & 7;
    const int idx = blockIdx.x >> 3;
    const int blk = xcd * ((B_SZ * T_LEN / CHUNK) >> 3) + idx;

    const int b    = blk / (T_LEN / CHUNK);
    const int t0   = (blk % (T_LEN / CHUNK)) * CHUNK;
    const int c    = threadIdx.x;          // rope pair index 0..511
    const int d0   = c * 2;
    const uint64_t bbase = (uint64_t)b * T_LEN;

    // ---- batched loads: 15 taps + 8 x_b, all issued before any use ----
    unsigned int tap[CHUNK + 7];
    unsigned int xbv[CHUNK];
    #pragma unroll
    for (int i = 0; i < CHUNK + 7; ++i) {
        int tj = t0 - 3 + i;
        int ta = tj < 0 ? 0 : (tj >= T_LEN ? T_LEN - 1 : tj);
        tap[i] = *reinterpret_cast<const unsigned int*>(projb + (bbase + ta) * NPROJ + d0);
    }
    #pragma unroll
    for (int r = 0; r < CHUNK; ++r) {
        xbv[r] = *reinterpret_cast<const unsigned int*>(projb + (bbase + t0 + r) * NPROJ + D_MODEL + d0);
    }

    // invf = 10000^(-c/512); trig at t0-3 then incremental rotation per tap
    const float invf = exp2f((float)c * (-13.287712379549449f / 512.0f));
    float sn, cs, sF, cF;
    __sincosf((float)(t0 - 3) * invf, &sn, &cs);
    __sincosf(invf, &sF, &cF);

    float kwv[7][2];
    #pragma unroll
    for (int j = 0; j < 7; j++) {
        kwv[j][0] = kw[j * D_MODEL + d0];
        kwv[j][1] = kw[j * D_MODEL + d0 + 1];
    }
    const float bv0 = dwb[d0], bv1 = dwb[d0 + 1];
    const float gm0 = gamma[d0], gm1 = gamma[d0 + 1];

    __shared__ float partial[CHUNK][8];
    __shared__ float invr[CHUNK];

    // ---- rope all taps (register-only after loads) ----
    float rx[CHUNK + 7][2];
    #pragma unroll
    for (int i = 0; i < CHUNK + 7; ++i) {
        const int tj = t0 - 3 + i;
        const bool valid = (unsigned)tj < (unsigned)T_LEN;
        float x0 = bf2f((unsigned short)(tap[i] & 0xffffu));
        float x1 = bf2f((unsigned short)(tap[i] >> 16));
        float r0 = x0 * cs - x1 * sn;
        float r1 = x0 * sn + x1 * cs;
        rx[i][0] = valid ? r0 : 0.f;
        rx[i][1] = valid ? r1 : 0.f;
        float c2 = cs * cF - sn * sF;      // advance angle by invf
        sn = sn * cF + cs * sF;
        cs = c2;
    }

    // ---- conv + SiLU + gate + wave-reduce (no barriers) ----
    float ga[CHUNK], gb[CHUNK];
    #pragma unroll
    for (int r = 0; r < CHUNK; ++r) {
        float acc0 = bv0, acc1 = bv1;
        #pragma unroll
        for (int j = 0; j < 7; j++) {
            acc0 += rx[r + j][0] * kwv[j][0];
            acc1 += rx[r + j][1] * kwv[j][1];
        }
        float a0 = acc0 * sigmoidf(acc0);
        float a1 = acc1 * sigmoidf(acc1);
        float g0 = a0 * sigmoidf(bf2f((unsigned short)(xbv[r] & 0xffffu)));
        float g1 = a1 * sigmoidf(bf2f((unsigned short)(xbv[r] >> 16)));
        ga[r] = g0; gb[r] = g1;

        float ssq = g0 * g0 + g1 * g1;
        #pragma unroll
        for (int off = 32; off; off >>= 1) ssq += __shfl_down(ssq, off);
        if ((c & 63) == 0) partial[r][c >> 6] = ssq;
    }

    __syncthreads();
    if (c < CHUNK) {
        float s = partial[c][0] + partial[c][1] + partial[c][2] + partial[c][3]
                + partial[c][4] + partial[c][5] + partial[c][6] + partial[c][7];
        invr[c] = 1.0f / sqrtf(s * (1.0f / (float)D_MODEL) + 1e-8f);
    }
    __syncthreads();

    #pragma unroll
    for (int r = 0; r < CHUNK; ++r) {
        const float iv = invr[r];
        float2 o;
        o.x = ga[r] * iv * gm0;
        o.y = gb[r] * iv * gm1;
        *reinterpret_cast<float2*>(out + (bbase + t0 + r) * D_MODEL + d0) = o;
    }
}

extern "C" void kernel_launch(void* const* d_in, const int* in_sizes, int n_in,
                              void* d_out, int out_size, void* d_ws, size_t ws_size,
                              hipStream_t stream) {
    const float* x     = (const float*)d_in[0];
    const float* sinp  = (const float*)d_in[1];   // unused: trig computed on the fly
    const float* cosp  = (const float*)d_in[2];   // unused
    const float* W     = (const float*)d_in[3];
    const float* bproj = (const float*)d_in[4];
    const float* dwk   = (const float*)d_in[5];
    const float* dwb   = (const float*)d_in[6];
    const float* gamma = (const float*)d_in[7];
    float* out = (float*)d_out;
    (void)sinp; (void)cosp;

    unsigned short* xb    = (unsigned short*)d_ws;                       // 32 MB
    unsigned short* wt    = xb + (size_t)NROWS * D_MODEL;                // 4 MB
    unsigned short* projb = wt + (size_t)NPROJ * D_MODEL;                // 64 MB

    const int cvt_w_blocks = (NPROJ / 32) * (D_MODEL / 32);              // 2048
    k_cvt<<<CVT_X_BLOCKS + cvt_w_blocks, 256, 0, stream>>>(x, xb, W, wt);
    k_gemm<<<(NPROJ / BN) * (NROWS / BM), 1024, 0, stream>>>(xb, wt, bproj, projb);
    k_post<<<B_SZ * (T_LEN / CHUNK), 512, 0, stream>>>(projb, dwk, dwb, gamma, out);
}

// Round 14
// 130.560 us; speedup vs baseline: 1.1775x; 1.0318x over previous
//
#include <hip/hip_runtime.h>
#include <stdint.h>

#define D_MODEL 1024
#define T_LEN   4096
#define B_SZ    4
#define NROWS   (B_SZ * T_LEN)   // 16384
#define NPROJ   (2 * D_MODEL)    // 2048
#define CHUNK   8                // rows of T per k_post block

#define BM 256
#define BN 256
#define BK 64
#define NT (D_MODEL / BK)        // 16 K-steps

typedef __attribute__((ext_vector_type(8))) __bf16 bf16x8;
typedef __attribute__((ext_vector_type(4))) float  f32x4;

using as1_void = __attribute__((address_space(1))) void;
using as3_void = __attribute__((address_space(3))) void;

__device__ inline float bf2f(unsigned short u) {
    union { unsigned int i; float f; } v; v.i = ((unsigned int)u) << 16; return v.f;
}
__device__ inline unsigned short f2bf(float f) {
    union { float f; unsigned int i; } v; v.f = f;
    return (unsigned short)((v.i + 0x7fffu + ((v.i >> 16) & 1u)) >> 16);
}
__device__ inline unsigned int f2bf2(float lo, float hi) {
    return (unsigned int)f2bf(lo) | ((unsigned int)f2bf(hi) << 16);
}
__device__ inline float sigmoidf(float x) { return 1.0f / (1.0f + __expf(-x)); }

// ---------------- K0: fused converts (x fp32->bf16 8/thread, W fp32->bf16 transposed) ----------------
#define CVT_X_BLOCKS ((NROWS * D_MODEL) / (256 * 8))   // 8192
__global__ __launch_bounds__(256) void k_cvt(const float* __restrict__ x,
                                             unsigned short* __restrict__ xb,
                                             const float* __restrict__ W,
                                             unsigned short* __restrict__ wt) {
    __shared__ unsigned short tile[32][33];
    int bid = blockIdx.x;
    if (bid < CVT_X_BLOCKS) {
        int i = (bid * 256 + threadIdx.x) * 8;
        float4 v0 = *reinterpret_cast<const float4*>(x + i);
        float4 v1 = *reinterpret_cast<const float4*>(x + i + 4);
        uint4 o;
        o.x = f2bf2(v0.x, v0.y);
        o.y = f2bf2(v0.z, v0.w);
        o.z = f2bf2(v1.x, v1.y);
        o.w = f2bf2(v1.z, v1.w);
        *reinterpret_cast<uint4*>(xb + i) = o;
    } else {
        bid -= CVT_X_BLOCKS;
        int n0 = (bid & 63) * 32, k0 = (bid >> 6) * 32;
        int c = threadIdx.x & 31, r = threadIdx.x >> 5;  // r in 0..7
        #pragma unroll
        for (int i = 0; i < 4; i++) {
            int kk = r + i * 8;
            tile[kk][c] = f2bf(W[(uint64_t)(k0 + kk) * NPROJ + n0 + c]);
        }
        __syncthreads();
        #pragma unroll
        for (int i = 0; i < 4; i++) {
            int nn = r + i * 8;
            wt[(uint64_t)(n0 + nn) * D_MODEL + k0 + c] = tile[c][nn];
        }
    }
}

// ---------------- K1: GEMM proj = xb @ wt^T + bias, store bf16 ----------------
// EXACT R3 kernel (verified 85.5us x7 runs, 0 bank conflicts). R13 proved
// occupancy is not the limiter (16-wave/38%-occ variant was SLOWER); the
// 2-phase barrier drain is structural. DO NOT touch body or epilogue.
__global__ __launch_bounds__(512, 2) void k_gemm(const unsigned short* __restrict__ xb,
                                                 const unsigned short* __restrict__ wt,
                                                 const float* __restrict__ bias,
                                                 unsigned short* __restrict__ projb) {
    __shared__ __align__(16) unsigned short As[2 * BM * BK];  // 64 KB
    __shared__ __align__(16) unsigned short Bs[2 * BM * BK];  // 64 KB

    const int tid  = threadIdx.x;
    const int lane = tid & 63;
    const int w    = tid >> 6;       // wave 0..7
    const int wm   = w >> 2;         // 0..1  (M half)
    const int wn   = w & 3;          // 0..3  (N quarter)

    // T1: 512 blocks = 8 n-tiles x 64 m-tiles; XCD k owns n-column k.
    const int bid = blockIdx.x;
    const int wg  = (bid & 7) * 64 + (bid >> 3);
    const int n0  = (wg >> 6) * BN;
    const int m0  = (wg & 63) * BM;

    const int srow = tid >> 3;                        // LDS row (mod 64) this thread fills
    const int scol = ((tid & 7) ^ (srow & 7)) * 8;    // T2: inverse-swizzled global col
    const int fr   = lane & 15;
    const int fq   = lane >> 4;

    f32x4 acc[8][4] = {};

    auto STAGE = [&](int buf, int ks) {
        #pragma unroll
        for (int i = 0; i < 4; ++i) {
            const unsigned short* ga = xb + (uint64_t)(m0 + i * 64 + srow) * D_MODEL + ks + scol;
            __builtin_amdgcn_global_load_lds((as1_void*)(void*)ga,
                (as3_void*)(void*)&As[buf * (BM * BK) + i * 4096 + w * 512], 16, 0, 0);
        }
        #pragma unroll
        for (int i = 0; i < 4; ++i) {
            const unsigned short* gb = wt + (uint64_t)(n0 + i * 64 + srow) * D_MODEL + ks + scol;
            __builtin_amdgcn_global_load_lds((as1_void*)(void*)gb,
                (as3_void*)(void*)&Bs[buf * (BM * BK) + i * 4096 + w * 512], 16, 0, 0);
        }
    };

    STAGE(0, 0);
    __syncthreads();

    for (int t = 0; t < NT; ++t) {
        const int cur = t & 1;
        if (t + 1 < NT) STAGE(1 - cur, (t + 1) * BK);   // issue-first prefetch

        const unsigned short* Ab = &As[cur * (BM * BK)];
        const unsigned short* Bb = &Bs[cur * (BM * BK)];
        #pragma unroll
        for (int kk = 0; kk < BK; kk += 32) {
            const int slot = (kk >> 3) + fq;            // global k-octet
            bf16x8 b[4];
            #pragma unroll
            for (int n = 0; n < 4; n++) {
                const int rb = wn * 64 + n * 16 + fr;
                b[n] = *reinterpret_cast<const bf16x8*>(&Bb[rb * 64 + ((slot ^ (fr & 7)) * 8)]);
            }
            #pragma unroll
            for (int m = 0; m < 8; m++) {
                const int ra = wm * 128 + m * 16 + fr;
                bf16x8 a = *reinterpret_cast<const bf16x8*>(&Ab[ra * 64 + ((slot ^ (fr & 7)) * 8)]);
                #pragma unroll
                for (int n = 0; n < 4; n++)
                    acc[m][n] = __builtin_amdgcn_mfma_f32_16x16x32_bf16(a, b[n], acc[m][n], 0, 0, 0);
            }
        }
        __syncthreads();
    }

    // epilogue: D layout col=lane&15, row=(lane>>4)*4+reg  [verified m89/m91]
    #pragma unroll
    for (int m = 0; m < 8; m++) {
        const int grow = m0 + wm * 128 + m * 16 + fq * 4;
        #pragma unroll
        for (int n = 0; n < 4; n++) {
            const int gcol = n0 + wn * 64 + n * 16 + fr;
            const float bv = bias[gcol];
            #pragma unroll
            for (int r = 0; r < 4; r++) {
                projb[(uint64_t)(grow + r) * NPROJ + gcol] = f2bf(acc[m][n][r] + bv);
            }
        }
    }
}

// ---------------- K2: batched-load two-phase RoPE + conv7 + SiLU + gate + RMSNorm ----------------
// R12 structure + T1 XCD swizzle (R13: -4us): neighbor t-chunks share an XCD
// so the 7-row halo re-read hits L2 instead of HBM.
__global__ __launch_bounds__(512) void k_post(const unsigned short* __restrict__ projb,
                                              const float* __restrict__ kw,
                                              const float* __restrict__ dwb,
                                              const float* __restrict__ gamma,
                                              float* __restrict__ out) {
    // bijective XCD swizzle: 2048 blocks, 256 contiguous chunks per XCD
    const int xcd = blockIdx.x & 7;
    const int idx = blockIdx.x >> 3;
    const int blk = xcd * ((B_SZ * T_LEN / CHUNK) >> 3) + idx;

    const int b    = blk / (T_LEN / CHUNK);
    const int t0   = (blk % (T_LEN / CHUNK)) * CHUNK;
    const int c    = threadIdx.x;          // rope pair index 0..511
    const int d0   = c * 2;
    const uint64_t bbase = (uint64_t)b * T_LEN;

    // ---- batched loads: 15 taps + 8 x_b, all issued before any use ----
    unsigned int tap[CHUNK + 7];
    unsigned int xbv[CHUNK];
    #pragma unroll
    for (int i = 0; i < CHUNK + 7; ++i) {
        int tj = t0 - 3 + i;
        int ta = tj < 0 ? 0 : (tj >= T_LEN ? T_LEN - 1 : tj);
        tap[i] = *reinterpret_cast<const unsigned int*>(projb + (bbase + ta) * NPROJ + d0);
    }
    #pragma unroll
    for (int r = 0; r < CHUNK; ++r) {
        xbv[r] = *reinterpret_cast<const unsigned int*>(projb + (bbase + t0 + r) * NPROJ + D_MODEL + d0);
    }

    // invf = 10000^(-c/512); trig at t0-3 then incremental rotation per tap
    const float invf = exp2f((float)c * (-13.287712379549449f / 512.0f));
    float sn, cs, sF, cF;
    __sincosf((float)(t0 - 3) * invf, &sn, &cs);
    __sincosf(invf, &sF, &cF);

    float kwv[7][2];
    #pragma unroll
    for (int j = 0; j < 7; j++) {
        kwv[j][0] = kw[j * D_MODEL + d0];
        kwv[j][1] = kw[j * D_MODEL + d0 + 1];
    }
    const float bv0 = dwb[d0], bv1 = dwb[d0 + 1];
    const float gm0 = gamma[d0], gm1 = gamma[d0 + 1];

    __shared__ float partial[CHUNK][8];
    __shared__ float invr[CHUNK];

    // ---- rope all taps (register-only after loads) ----
    float rx[CHUNK + 7][2];
    #pragma unroll
    for (int i = 0; i < CHUNK + 7; ++i) {
        const int tj = t0 - 3 + i;
        const bool valid = (unsigned)tj < (unsigned)T_LEN;
        float x0 = bf2f((unsigned short)(tap[i] & 0xffffu));
        float x1 = bf2f((unsigned short)(tap[i] >> 16));
        float r0 = x0 * cs - x1 * sn;
        float r1 = x0 * sn + x1 * cs;
        rx[i][0] = valid ? r0 : 0.f;
        rx[i][1] = valid ? r1 : 0.f;
        float c2 = cs * cF - sn * sF;      // advance angle by invf
        sn = sn * cF + cs * sF;
        cs = c2;
    }

    // ---- conv + SiLU + gate + wave-reduce (no barriers) ----
    float ga[CHUNK], gb[CHUNK];
    #pragma unroll
    for (int r = 0; r < CHUNK; ++r) {
        float acc0 = bv0, acc1 = bv1;
        #pragma unroll
        for (int j = 0; j < 7; j++) {
            acc0 += rx[r + j][0] * kwv[j][0];
            acc1 += rx[r + j][1] * kwv[j][1];
        }
        float a0 = acc0 * sigmoidf(acc0);
        float a1 = acc1 * sigmoidf(acc1);
        float g0 = a0 * sigmoidf(bf2f((unsigned short)(xbv[r] & 0xffffu)));
        float g1 = a1 * sigmoidf(bf2f((unsigned short)(xbv[r] >> 16)));
        ga[r] = g0; gb[r] = g1;

        float ssq = g0 * g0 + g1 * g1;
        #pragma unroll
        for (int off = 32; off; off >>= 1) ssq += __shfl_down(ssq, off);
        if ((c & 63) == 0) partial[r][c >> 6] = ssq;
    }

    __syncthreads();
    if (c < CHUNK) {
        float s = partial[c][0] + partial[c][1] + partial[c][2] + partial[c][3]
                + partial[c][4] + partial[c][5] + partial[c][6] + partial[c][7];
        invr[c] = 1.0f / sqrtf(s * (1.0f / (float)D_MODEL) + 1e-8f);
    }
    __syncthreads();

    #pragma unroll
    for (int r = 0; r < CHUNK; ++r) {
        const float iv = invr[r];
        float2 o;
        o.x = ga[r] * iv * gm0;
        o.y = gb[r] * iv * gm1;
        *reinterpret_cast<float2*>(out + (bbase + t0 + r) * D_MODEL + d0) = o;
    }
}

extern "C" void kernel_launch(void* const* d_in, const int* in_sizes, int n_in,
                              void* d_out, int out_size, void* d_ws, size_t ws_size,
                              hipStream_t stream) {
    const float* x     = (const float*)d_in[0];
    const float* sinp  = (const float*)d_in[1];   // unused: trig computed on the fly
    const float* cosp  = (const float*)d_in[2];   // unused
    const float* W     = (const float*)d_in[3];
    const float* bproj = (const float*)d_in[4];
    const float* dwk   = (const float*)d_in[5];
    const float* dwb   = (const float*)d_in[6];
    const float* gamma = (const float*)d_in[7];
    float* out = (float*)d_out;
    (void)sinp; (void)cosp;

    unsigned short* xb    = (unsigned short*)d_ws;                       // 32 MB
    unsigned short* wt    = xb + (size_t)NROWS * D_MODEL;                // 4 MB
    unsigned short* projb = wt + (size_t)NPROJ * D_MODEL;                // 64 MB

    const int cvt_w_blocks = (NPROJ / 32) * (D_MODEL / 32);              // 2048
    k_cvt<<<CVT_X_BLOCKS + cvt_w_blocks, 256, 0, stream>>>(x, xb, W, wt);
    k_gemm<<<(NPROJ / BN) * (NROWS / BM), 512, 0, stream>>>(xb, wt, bproj, projb);
    k_post<<<B_SZ * (T_LEN / CHUNK), 512, 0, stream>>>(projb, dwk, dwb, gamma, out);
}

// Round 15
// 128.864 us; speedup vs baseline: 1.1930x; 1.0132x over previous
//
#include <hip/hip_runtime.h>
#include <stdint.h>

#define D_MODEL 1024
#define T_LEN   4096
#define B_SZ    4
#define NROWS   (B_SZ * T_LEN)   // 16384
#define NPROJ   (2 * D_MODEL)    // 2048
#define CHUNK   8                // rows of T per k_post block

#define BM 256
#define BN 256
#define BK 64
#define NT (D_MODEL / BK)        // 16 K-steps

typedef __attribute__((ext_vector_type(8))) __bf16 bf16x8;
typedef __attribute__((ext_vector_type(4))) float  f32x4;

using as1_void = __attribute__((address_space(1))) void;
using as3_void = __attribute__((address_space(3))) void;

__device__ inline float bf2f(unsigned short u) {
    union { unsigned int i; float f; } v; v.i = ((unsigned int)u) << 16; return v.f;
}
__device__ inline unsigned short f2bf(float f) {
    union { float f; unsigned int i; } v; v.f = f;
    return (unsigned short)((v.i + 0x7fffu + ((v.i >> 16) & 1u)) >> 16);
}
__device__ inline unsigned int f2bf2(float lo, float hi) {
    return (unsigned int)f2bf(lo) | ((unsigned int)f2bf(hi) << 16);
}
__device__ inline float sigmoidf(float x) { return 1.0f / (1.0f + __expf(-x)); }

// ---------------- K0: fused converts (x fp32->bf16 8/thread, W fp32->bf16 transposed) ----------------
#define CVT_X_BLOCKS ((NROWS * D_MODEL) / (256 * 8))   // 8192
__global__ __launch_bounds__(256) void k_cvt(const float* __restrict__ x,
                                             unsigned short* __restrict__ xb,
                                             const float* __restrict__ W,
                                             unsigned short* __restrict__ wt) {
    __shared__ unsigned short tile[32][33];
    int bid = blockIdx.x;
    if (bid < CVT_X_BLOCKS) {
        int i = (bid * 256 + threadIdx.x) * 8;
        float4 v0 = *reinterpret_cast<const float4*>(x + i);
        float4 v1 = *reinterpret_cast<const float4*>(x + i + 4);
        uint4 o;
        o.x = f2bf2(v0.x, v0.y);
        o.y = f2bf2(v0.z, v0.w);
        o.z = f2bf2(v1.x, v1.y);
        o.w = f2bf2(v1.z, v1.w);
        *reinterpret_cast<uint4*>(xb + i) = o;
    } else {
        bid -= CVT_X_BLOCKS;
        int n0 = (bid & 63) * 32, k0 = (bid >> 6) * 32;
        int c = threadIdx.x & 31, r = threadIdx.x >> 5;  // r in 0..7
        #pragma unroll
        for (int i = 0; i < 4; i++) {
            int kk = r + i * 8;
            tile[kk][c] = f2bf(W[(uint64_t)(k0 + kk) * NPROJ + n0 + c]);
        }
        __syncthreads();
        #pragma unroll
        for (int i = 0; i < 4; i++) {
            int nn = r + i * 8;
            wt[(uint64_t)(n0 + nn) * D_MODEL + k0 + c] = tile[c][nn];
        }
    }
}

// ---------------- K1: GEMM proj = xb @ wt^T + bias, store bf16 ----------------
// R3 body (verified 85.5us x8, 0 bank conflicts). ONLY change vs R14: the
// T1 block->tile mapping is m-CLUSTERED per XCD (XCD k owns m-tiles
// [8k,8k+8) x all 8 n-tiles) so A-tiles get 8-way reuse in the XCD's
// private L2 instead of every XCD streaming the full 32MB A. Index-only
// change; K-loop and epilogue untouched.
__global__ __launch_bounds__(512, 2) void k_gemm(const unsigned short* __restrict__ xb,
                                                 const unsigned short* __restrict__ wt,
                                                 const float* __restrict__ bias,
                                                 unsigned short* __restrict__ projb) {
    __shared__ __align__(16) unsigned short As[2 * BM * BK];  // 64 KB
    __shared__ __align__(16) unsigned short Bs[2 * BM * BK];  // 64 KB

    const int tid  = threadIdx.x;
    const int lane = tid & 63;
    const int w    = tid >> 6;       // wave 0..7
    const int wm   = w >> 2;         // 0..1  (M half)
    const int wn   = w & 3;          // 0..3  (N quarter)

    // T1 (m-clustered): 512 blocks; XCD = bid&7 owns m-tiles [xcd*8, xcd*8+8)
    // crossed with all 8 n-tiles. Bijective (512 % 8 == 0).
    const int bid = blockIdx.x;
    const int xcd = bid & 7;
    const int idx = bid >> 3;                  // 0..63
    const int m0  = (xcd * 8 + (idx >> 3)) * BM;
    const int n0  = (idx & 7) * BN;

    const int srow = tid >> 3;                        // LDS row (mod 64) this thread fills
    const int scol = ((tid & 7) ^ (srow & 7)) * 8;    // T2: inverse-swizzled global col
    const int fr   = lane & 15;
    const int fq   = lane >> 4;

    f32x4 acc[8][4] = {};

    auto STAGE = [&](int buf, int ks) {
        #pragma unroll
        for (int i = 0; i < 4; ++i) {
            const unsigned short* ga = xb + (uint64_t)(m0 + i * 64 + srow) * D_MODEL + ks + scol;
            __builtin_amdgcn_global_load_lds((as1_void*)(void*)ga,
                (as3_void*)(void*)&As[buf * (BM * BK) + i * 4096 + w * 512], 16, 0, 0);
        }
        #pragma unroll
        for (int i = 0; i < 4; ++i) {
            const unsigned short* gb = wt + (uint64_t)(n0 + i * 64 + srow) * D_MODEL + ks + scol;
            __builtin_amdgcn_global_load_lds((as1_void*)(void*)gb,
                (as3_void*)(void*)&Bs[buf * (BM * BK) + i * 4096 + w * 512], 16, 0, 0);
        }
    };

    STAGE(0, 0);
    __syncthreads();

    for (int t = 0; t < NT; ++t) {
        const int cur = t & 1;
        if (t + 1 < NT) STAGE(1 - cur, (t + 1) * BK);   // issue-first prefetch

        const unsigned short* Ab = &As[cur * (BM * BK)];
        const unsigned short* Bb = &Bs[cur * (BM * BK)];
        #pragma unroll
        for (int kk = 0; kk < BK; kk += 32) {
            const int slot = (kk >> 3) + fq;            // global k-octet
            bf16x8 b[4];
            #pragma unroll
            for (int n = 0; n < 4; n++) {
                const int rb = wn * 64 + n * 16 + fr;
                b[n] = *reinterpret_cast<const bf16x8*>(&Bb[rb * 64 + ((slot ^ (fr & 7)) * 8)]);
            }
            #pragma unroll
            for (int m = 0; m < 8; m++) {
                const int ra = wm * 128 + m * 16 + fr;
                bf16x8 a = *reinterpret_cast<const bf16x8*>(&Ab[ra * 64 + ((slot ^ (fr & 7)) * 8)]);
                #pragma unroll
                for (int n = 0; n < 4; n++)
                    acc[m][n] = __builtin_amdgcn_mfma_f32_16x16x32_bf16(a, b[n], acc[m][n], 0, 0, 0);
            }
        }
        __syncthreads();
    }

    // epilogue: D layout col=lane&15, row=(lane>>4)*4+reg  [verified m89/m91]
    #pragma unroll
    for (int m = 0; m < 8; m++) {
        const int grow = m0 + wm * 128 + m * 16 + fq * 4;
        #pragma unroll
        for (int n = 0; n < 4; n++) {
            const int gcol = n0 + wn * 64 + n * 16 + fr;
            const float bv = bias[gcol];
            #pragma unroll
            for (int r = 0; r < 4; r++) {
                projb[(uint64_t)(grow + r) * NPROJ + gcol] = f2bf(acc[m][n][r] + bv);
            }
        }
    }
}

// ---------------- K2: batched-load two-phase RoPE + conv7 + SiLU + gate + RMSNorm ----------------
// R12 structure + T1 XCD swizzle (R13: -4us): neighbor t-chunks share an XCD
// so the 7-row halo re-read hits L2 instead of HBM.
__global__ __launch_bounds__(512) void k_post(const unsigned short* __restrict__ projb,
                                              const float* __restrict__ kw,
                                              const float* __restrict__ dwb,
                                              const float* __restrict__ gamma,
                                              float* __restrict__ out) {
    // bijective XCD swizzle: 2048 blocks, 256 contiguous chunks per XCD
    const int xcd = blockIdx.x & 7;
    const int idx = blockIdx.x >> 3;
    const int blk = xcd * ((B_SZ * T_LEN / CHUNK) >> 3) + idx;

    const int b    = blk / (T_LEN / CHUNK);
    const int t0   = (blk % (T_LEN / CHUNK)) * CHUNK;
    const int c    = threadIdx.x;          // rope pair index 0..511
    const int d0   = c * 2;
    const uint64_t bbase = (uint64_t)b * T_LEN;

    // ---- batched loads: 15 taps + 8 x_b, all issued before any use ----
    unsigned int tap[CHUNK + 7];
    unsigned int xbv[CHUNK];
    #pragma unroll
    for (int i = 0; i < CHUNK + 7; ++i) {
        int tj = t0 - 3 + i;
        int ta = tj < 0 ? 0 : (tj >= T_LEN ? T_LEN - 1 : tj);
        tap[i] = *reinterpret_cast<const unsigned int*>(projb + (bbase + ta) * NPROJ + d0);
    }
    #pragma unroll
    for (int r = 0; r < CHUNK; ++r) {
        xbv[r] = *reinterpret_cast<const unsigned int*>(projb + (bbase + t0 + r) * NPROJ + D_MODEL + d0);
    }

    // invf = 10000^(-c/512); trig at t0-3 then incremental rotation per tap
    const float invf = exp2f((float)c * (-13.287712379549449f / 512.0f));
    float sn, cs, sF, cF;
    __sincosf((float)(t0 - 3) * invf, &sn, &cs);
    __sincosf(invf, &sF, &cF);

    float kwv[7][2];
    #pragma unroll
    for (int j = 0; j < 7; j++) {
        kwv[j][0] = kw[j * D_MODEL + d0];
        kwv[j][1] = kw[j * D_MODEL + d0 + 1];
    }
    const float bv0 = dwb[d0], bv1 = dwb[d0 + 1];
    const float gm0 = gamma[d0], gm1 = gamma[d0 + 1];

    __shared__ float partial[CHUNK][8];
    __shared__ float invr[CHUNK];

    // ---- rope all taps (register-only after loads) ----
    float rx[CHUNK + 7][2];
    #pragma unroll
    for (int i = 0; i < CHUNK + 7; ++i) {
        const int tj = t0 - 3 + i;
        const bool valid = (unsigned)tj < (unsigned)T_LEN;
        float x0 = bf2f((unsigned short)(tap[i] & 0xffffu));
        float x1 = bf2f((unsigned short)(tap[i] >> 16));
        float r0 = x0 * cs - x1 * sn;
        float r1 = x0 * sn + x1 * cs;
        rx[i][0] = valid ? r0 : 0.f;
        rx[i][1] = valid ? r1 : 0.f;
        float c2 = cs * cF - sn * sF;      // advance angle by invf
        sn = sn * cF + cs * sF;
        cs = c2;
    }

    // ---- conv + SiLU + gate + wave-reduce (no barriers) ----
    float ga[CHUNK], gb[CHUNK];
    #pragma unroll
    for (int r = 0; r < CHUNK; ++r) {
        float acc0 = bv0, acc1 = bv1;
        #pragma unroll
        for (int j = 0; j < 7; j++) {
            acc0 += rx[r + j][0] * kwv[j][0];
            acc1 += rx[r + j][1] * kwv[j][1];
        }
        float a0 = acc0 * sigmoidf(acc0);
        float a1 = acc1 * sigmoidf(acc1);
        float g0 = a0 * sigmoidf(bf2f((unsigned short)(xbv[r] & 0xffffu)));
        float g1 = a1 * sigmoidf(bf2f((unsigned short)(xbv[r] >> 16)));
        ga[r] = g0; gb[r] = g1;

        float ssq = g0 * g0 + g1 * g1;
        #pragma unroll
        for (int off = 32; off; off >>= 1) ssq += __shfl_down(ssq, off);
        if ((c & 63) == 0) partial[r][c >> 6] = ssq;
    }

    __syncthreads();
    if (c < CHUNK) {
        float s = partial[c][0] + partial[c][1] + partial[c][2] + partial[c][3]
                + partial[c][4] + partial[c][5] + partial[c][6] + partial[c][7];
        invr[c] = 1.0f / sqrtf(s * (1.0f / (float)D_MODEL) + 1e-8f);
    }
    __syncthreads();

    #pragma unroll
    for (int r = 0; r < CHUNK; ++r) {
        const float iv = invr[r];
        float2 o;
        o.x = ga[r] * iv * gm0;
        o.y = gb[r] * iv * gm1;
        *reinterpret_cast<float2*>(out + (bbase + t0 + r) * D_MODEL + d0) = o;
    }
}

extern "C" void kernel_launch(void* const* d_in, const int* in_sizes, int n_in,
                              void* d_out, int out_size, void* d_ws, size_t ws_size,
                              hipStream_t stream) {
    const float* x     = (const float*)d_in[0];
    const float* sinp  = (const float*)d_in[1];   // unused: trig computed on the fly
    const float* cosp  = (const float*)d_in[2];   // unused
    const float* W     = (const float*)d_in[3];
    const float* bproj = (const float*)d_in[4];
    const float* dwk   = (const float*)d_in[5];
    const float* dwb   = (const float*)d_in[6];
    const float* gamma = (const float*)d_in[7];
    float* out = (float*)d_out;
    (void)sinp; (void)cosp;

    unsigned short* xb    = (unsigned short*)d_ws;                       // 32 MB
    unsigned short* wt    = xb + (size_t)NROWS * D_MODEL;                // 4 MB
    unsigned short* projb = wt + (size_t)NPROJ * D_MODEL;                // 64 MB

    const int cvt_w_blocks = (NPROJ / 32) * (D_MODEL / 32);              // 2048
    k_cvt<<<CVT_X_BLOCKS + cvt_w_blocks, 256, 0, stream>>>(x, xb, W, wt);
    k_gemm<<<(NPROJ / BN) * (NROWS / BM), 512, 0, stream>>>(xb, wt, bproj, projb);
    k_post<<<B_SZ * (T_LEN / CHUNK), 512, 0, stream>>>(projb, dwk, dwb, gamma, out);
}